// Round 1
// baseline (200.919 us; speedup 1.0000x reference)
//
#include <hip/hip_runtime.h>
#include <hip/hip_bf16.h>
#include <math.h>

typedef __bf16 bf16;
typedef __bf16 bf16x4 __attribute__((ext_vector_type(4)));
typedef __bf16 bf16x8 __attribute__((ext_vector_type(8)));
typedef float f32x4 __attribute__((ext_vector_type(4)));
typedef unsigned short ushort8 __attribute__((ext_vector_type(8)));

#define MFMA16(a, b, c) __builtin_amdgcn_mfma_f32_16x16x32_bf16(a, b, c, 0, 0, 0)

__device__ inline bf16x8 frag2(bf16x4 a, bf16x4 b) {
    bf16x8 r;
    r[0] = a[0]; r[1] = a[1]; r[2] = a[2]; r[3] = a[3];
    r[4] = b[0]; r[5] = b[1]; r[6] = b[2]; r[7] = b[3];
    return r;
}

__device__ inline bf16x8 frag_from(const bf16* p0, const bf16* p1) {
    return frag2(*(const bf16x4*)p0, *(const bf16x4*)p1);
}

// ---------------------------------------------------------------------------
// Kernel 1: QKV projections.  out[i][o] = sum_c in[c][i] * W[o][c] + b[o]
// in is [256][4096] (c-major), W is [256][256] [o][c], out bf16 [4096][256]
// grid (64, 4, 3): z selects Q(x)/K(y)/V(y)
// ---------------------------------------------------------------------------
__global__ __launch_bounds__(256) void k_qkv(
    const float* __restrict__ x, const float* __restrict__ y,
    const float* __restrict__ Wq, const float* __restrict__ bq,
    const float* __restrict__ Wk, const float* __restrict__ bk,
    const float* __restrict__ Wv, const float* __restrict__ bv,
    bf16* __restrict__ Qo, bf16* __restrict__ Ko, bf16* __restrict__ Vo)
{
    const int zi = blockIdx.z;
    const float* src  = (zi == 0) ? x : y;
    const float* W    = (zi == 0) ? Wq : (zi == 1 ? Wk : Wv);
    const float* bias = (zi == 0) ? bq : (zi == 1 ? bk : bv);
    bf16* dst         = (zi == 0) ? Qo : (zi == 1 ? Ko : Vo);

    const int i0 = blockIdx.x * 64;
    const int o0 = blockIdx.y * 64;
    const int t = threadIdx.x;
    const int lane = t & 63;
    const int w = t >> 6;
    const int wr = w >> 1, wc = w & 1;
    const int l16 = lane & 15, lg = lane >> 4;

    __shared__ bf16 As[64][40];   // [m][k] (transposed from global)
    __shared__ bf16 Bs[64][40];   // [n][k]

    f32x4 acc[2][2] = {};

    for (int kc = 0; kc < 256; kc += 32) {
        __syncthreads();
        for (int p = 0; p < 8; ++p) {
            int e = t + 256 * p;          // 0..2047
            int c = e >> 6, m = e & 63;
            As[m][c] = (bf16)(src[(kc + c) * 4096 + i0 + m]);
        }
        for (int p = 0; p < 8; ++p) {
            int e = t + 256 * p;
            int n = e >> 5, c = e & 31;
            Bs[n][c] = (bf16)(W[(o0 + n) * 256 + kc + c]);
        }
        __syncthreads();
        const int c0 = 4 * lg;
        bf16x8 af[2], bfr[2];
        for (int mi = 0; mi < 2; ++mi) {
            int m = 32 * wr + 16 * mi + l16;
            af[mi] = frag_from(&As[m][c0], &As[m][c0 + 16]);
        }
        for (int ni = 0; ni < 2; ++ni) {
            int n = 32 * wc + 16 * ni + l16;
            bfr[ni] = frag_from(&Bs[n][c0], &Bs[n][c0 + 16]);
        }
        for (int mi = 0; mi < 2; ++mi)
            for (int ni = 0; ni < 2; ++ni)
                acc[mi][ni] = MFMA16(af[mi], bfr[ni], acc[mi][ni]);
    }

    for (int mi = 0; mi < 2; ++mi)
        for (int ni = 0; ni < 2; ++ni) {
            int n = o0 + 32 * wc + 16 * ni + l16;
            float bv_ = bias[n];
            for (int i = 0; i < 4; ++i) {
                int m = i0 + 32 * wr + 16 * mi + 4 * lg + i;
                dst[m * 256 + n] = (bf16)(acc[mi][ni][i] + bv_);
            }
        }
}

// ---------------------------------------------------------------------------
// Kernel T: transpose V [4096][256] -> Vt [256][4096] (bf16)
// ---------------------------------------------------------------------------
__global__ __launch_bounds__(256) void k_transpose(
    const bf16* __restrict__ V, bf16* __restrict__ Vt)
{
    __shared__ bf16 tile[32][33];
    const int i0 = blockIdx.x * 32;   // key dim
    const int o0 = blockIdx.y * 32;   // d dim
    const int t = threadIdx.x;
    for (int p = 0; p < 4; ++p) {
        int e = t + 256 * p;
        int r = e >> 5, c = e & 31;
        tile[r][c] = V[(i0 + r) * 256 + o0 + c];
    }
    __syncthreads();
    for (int p = 0; p < 4; ++p) {
        int e = t + 256 * p;
        int r = e >> 5, c = e & 31;
        Vt[(o0 + r) * 4096 + i0 + c] = tile[c][r];
    }
}

// ---------------------------------------------------------------------------
// Kernel 2: flash attention. BQ=32 rows per block, KV tiles of 64.
// Q pre-scaled by 1/16. Q/K LDS rows XOR-swizzled (16B unit ^ ((row&7)<<4)).
// ---------------------------------------------------------------------------
__global__ __launch_bounds__(256) void k_flash(
    const bf16* __restrict__ Qg, const bf16* __restrict__ Kg,
    const bf16* __restrict__ Vtg, bf16* __restrict__ att)
{
    __shared__ char  Qs[32 * 512];
    __shared__ char  Ks[64 * 512];
    __shared__ bf16  Vts[256][72];    // [d][key], padded (144B rows)
    __shared__ float S_lds[32][72];
    __shared__ bf16  P_lds[32][68];   // [q][key], 136B rows
    __shared__ float m_l[32], l_l[32], corr_l[32];

    const int t = threadIdx.x;
    const int lane = t & 63;
    const int w = t >> 6;
    const int l16 = lane & 15, lg = lane >> 4;
    const int q0 = blockIdx.x * 32;

    // stage Q (scaled), swizzled
    for (int p = 0; p < 4; ++p) {
        int e = t + 256 * p;                       // 0..1023 units
        int r = e >> 5, u = e & 31;
        ushort8 v = *(const ushort8*)(Qg + (q0 + r) * 256 + 8 * u);
        bf16x8 bv = *(bf16x8*)&v;
        for (int j = 0; j < 8; ++j) bv[j] = (bf16)((float)bv[j] * 0.0625f);
        *(bf16x8*)&Qs[r * 512 + ((u * 16) ^ ((r & 7) << 4))] = bv;
    }
    if (t < 32) { m_l[t] = -INFINITY; l_l[t] = 0.f; }
    __syncthreads();

    // hoist Q fragments: [mi][ks]
    bf16x8 Qf[2][8];
    for (int mi = 0; mi < 2; ++mi) {
        int q = 16 * mi + l16;
        int rb = q * 512, sw = (q & 7) << 4;
        for (int ks = 0; ks < 8; ++ks) {
            int db0 = 64 * ks + 8 * lg;
            bf16x4 a0 = *(const bf16x4*)&Qs[rb + (db0 ^ sw)];
            bf16x4 a1 = *(const bf16x4*)&Qs[rb + ((db0 + 32) ^ sw)];
            Qf[mi][ks] = frag2(a0, a1);
        }
    }

    f32x4 O[2][4] = {};   // [mi][ni] -> rows 16mi.., cols 64w+16ni..

    for (int kv = 0; kv < 4096; kv += 64) {
        __syncthreads();
        for (int p = 0; p < 8; ++p) {               // stage K tile (swizzled)
            int e = t + 256 * p;                     // 0..2047
            int r = e >> 5, u = e & 31;
            ushort8 v = *(const ushort8*)(Kg + (kv + r) * 256 + 8 * u);
            *(ushort8*)&Ks[r * 512 + ((u * 16) ^ ((r & 7) << 4))] = v;
        }
        for (int p = 0; p < 8; ++p) {               // stage Vt tile
            int e = t + 256 * p;
            int d = e >> 3, u = e & 7;
            ushort8 v = *(const ushort8*)(Vtg + d * 4096 + kv + 8 * u);
            *(ushort8*)((char*)&Vts[d][0] + u * 16) = v;
        }
        __syncthreads();

        // S tile: this wave handles keys [16w, 16w+16)
        f32x4 Sacc[2] = {};
        {
            int key = 16 * w + l16;
            int rb = key * 512, sw = (key & 7) << 4;
            for (int ks = 0; ks < 8; ++ks) {
                int db0 = 64 * ks + 8 * lg;
                bf16x4 b0 = *(const bf16x4*)&Ks[rb + (db0 ^ sw)];
                bf16x4 b1 = *(const bf16x4*)&Ks[rb + ((db0 + 32) ^ sw)];
                bf16x8 bfr = frag2(b0, b1);
                for (int mi = 0; mi < 2; ++mi)
                    Sacc[mi] = MFMA16(Qf[mi][ks], bfr, Sacc[mi]);
            }
        }
        for (int mi = 0; mi < 2; ++mi)
            for (int i = 0; i < 4; ++i)
                S_lds[16 * mi + 4 * lg + i][16 * w + l16] = Sacc[mi][i];
        __syncthreads();

        // online softmax: 8 threads per row
        {
            int r = t >> 3, cb = (t & 7) * 8;
            float s[8];
            float mx = -INFINITY;
            for (int j = 0; j < 8; ++j) { s[j] = S_lds[r][cb + j]; mx = fmaxf(mx, s[j]); }
            mx = fmaxf(mx, __shfl_xor(mx, 1));
            mx = fmaxf(mx, __shfl_xor(mx, 2));
            mx = fmaxf(mx, __shfl_xor(mx, 4));
            float mo = m_l[r];
            float mn = fmaxf(mo, mx);
            float sum = 0.f;
            for (int j = 0; j < 8; ++j) { float p_ = __expf(s[j] - mn); s[j] = p_; sum += p_; }
            sum += __shfl_xor(sum, 1);
            sum += __shfl_xor(sum, 2);
            sum += __shfl_xor(sum, 4);
            if ((t & 7) == 0) {
                float corr = __expf(mo - mn);
                l_l[r] = l_l[r] * corr + sum;
                m_l[r] = mn;
                corr_l[r] = corr;
            }
            for (int j = 0; j < 8; ++j) P_lds[r][cb + j] = (bf16)s[j];
        }
        __syncthreads();

        // rescale O, then O += P @ V
        {
            float cr[2][4];
            for (int mi = 0; mi < 2; ++mi)
                for (int i = 0; i < 4; ++i)
                    cr[mi][i] = corr_l[16 * mi + 4 * lg + i];
            for (int mi = 0; mi < 2; ++mi)
                for (int ni = 0; ni < 4; ++ni)
                    for (int i = 0; i < 4; ++i)
                        O[mi][ni][i] *= cr[mi][i];
            for (int ks2 = 0; ks2 < 2; ++ks2) {
                int k0 = 32 * ks2 + 4 * lg;
                bf16x8 pa[2];
                for (int mi = 0; mi < 2; ++mi) {
                    int q = 16 * mi + l16;
                    pa[mi] = frag_from(&P_lds[q][k0], &P_lds[q][k0 + 16]);
                }
                for (int ni = 0; ni < 4; ++ni) {
                    int d = 64 * w + 16 * ni + l16;
                    bf16x8 vb = frag_from(&Vts[d][k0], &Vts[d][k0 + 16]);
                    for (int mi = 0; mi < 2; ++mi)
                        O[mi][ni] = MFMA16(pa[mi], vb, O[mi][ni]);
                }
            }
        }
    }

    float linv[2][4];
    for (int mi = 0; mi < 2; ++mi)
        for (int i = 0; i < 4; ++i)
            linv[mi][i] = 1.f / l_l[16 * mi + 4 * lg + i];
    for (int mi = 0; mi < 2; ++mi)
        for (int ni = 0; ni < 4; ++ni)
            for (int i = 0; i < 4; ++i) {
                int q = q0 + 16 * mi + 4 * lg + i;
                int d = 64 * w + 16 * ni + l16;
                att[q * 256 + d] = (bf16)(O[mi][ni][i] * linv[mi][i]);
            }
}

// ---------------------------------------------------------------------------
// Kernel 3: z = att @ Wo^T + bo, then LayerNorm over channels; BM=32 full row
// ---------------------------------------------------------------------------
__global__ __launch_bounds__(256) void k_proj_ln(
    const bf16* __restrict__ att, const float* __restrict__ Wo,
    const float* __restrict__ bo, const float* __restrict__ ln_w,
    const float* __restrict__ ln_b, bf16* __restrict__ zn)
{
    __shared__ bf16 As[32][40];
    __shared__ bf16 Bs[256][40];
    __shared__ float psum[4][32], psq[4][32];
    __shared__ float mean_l[32], inv_l[32];

    const int t = threadIdx.x, lane = t & 63, w = t >> 6;
    const int l16 = lane & 15, lg = lane >> 4;
    const int q0 = blockIdx.x * 32;

    f32x4 acc[2][4] = {};
    for (int kc = 0; kc < 256; kc += 32) {
        __syncthreads();
        if (t < 128) {
            int r = t >> 2, u = t & 3;
            ushort8 v = *(const ushort8*)(att + (q0 + r) * 256 + kc + 8 * u);
            *(ushort8*)((char*)&As[r][0] + 16 * u) = v;
        }
        for (int p = 0; p < 32; ++p) {
            int e = t + 256 * p;          // 0..8191
            int n = e >> 5, c = e & 31;
            Bs[n][c] = (bf16)(Wo[n * 256 + kc + c]);
        }
        __syncthreads();
        bf16x8 af[2];
        for (int mi = 0; mi < 2; ++mi) {
            int m = 16 * mi + l16;
            af[mi] = frag_from(&As[m][4 * lg], &As[m][4 * lg + 16]);
        }
        for (int ni = 0; ni < 4; ++ni) {
            int n = 64 * w + 16 * ni + l16;
            bf16x8 bfr = frag_from(&Bs[n][4 * lg], &Bs[n][4 * lg + 16]);
            for (int mi = 0; mi < 2; ++mi)
                acc[mi][ni] = MFMA16(af[mi], bfr, acc[mi][ni]);
        }
    }

    float z[2][4][4];
    float rs[2][4] = {}, rq[2][4] = {};
    for (int ni = 0; ni < 4; ++ni) {
        int n = 64 * w + 16 * ni + l16;
        float b_ = bo[n];
        for (int mi = 0; mi < 2; ++mi)
            for (int i = 0; i < 4; ++i) {
                float v = acc[mi][ni][i] + b_;
                z[mi][ni][i] = v;
                rs[mi][i] += v;
                rq[mi][i] += v * v;
            }
    }
    for (int mi = 0; mi < 2; ++mi)
        for (int i = 0; i < 4; ++i) {
            float s = rs[mi][i], q = rq[mi][i];
            for (int msk = 1; msk <= 8; msk <<= 1) {
                s += __shfl_xor(s, msk);
                q += __shfl_xor(q, msk);
            }
            if (l16 == 0) {
                psum[w][16 * mi + 4 * lg + i] = s;
                psq[w][16 * mi + 4 * lg + i]  = q;
            }
        }
    __syncthreads();
    if (t < 32) {
        float s = psum[0][t] + psum[1][t] + psum[2][t] + psum[3][t];
        float q = psq[0][t] + psq[1][t] + psq[2][t] + psq[3][t];
        float mean = s * (1.f / 256.f);
        float var = q * (1.f / 256.f) - mean * mean;
        mean_l[t] = mean;
        inv_l[t] = rsqrtf(var + 1e-6f);
    }
    __syncthreads();
    for (int ni = 0; ni < 4; ++ni) {
        int n = 64 * w + 16 * ni + l16;
        float g = ln_w[n], be = ln_b[n];
        for (int mi = 0; mi < 2; ++mi)
            for (int i = 0; i < 4; ++i) {
                int r = 16 * mi + 4 * lg + i;
                float v = (z[mi][ni][i] - mean_l[r]) * inv_l[r] * g + be;
                zn[(q0 + r) * 256 + n] = (bf16)v;
            }
    }
}

// ---------------------------------------------------------------------------
// Kernel 4: t1 = gelu(zn @ W1^T + b1), exact erf gelu. [4096][512] bf16 out
// ---------------------------------------------------------------------------
__global__ __launch_bounds__(256) void k_mlp1(
    const bf16* __restrict__ zn, const float* __restrict__ W1,
    const float* __restrict__ b1, bf16* __restrict__ t1)
{
    __shared__ bf16 As[64][40];
    __shared__ bf16 Bs[64][40];
    const int t = threadIdx.x, lane = t & 63, w = t >> 6;
    const int l16 = lane & 15, lg = lane >> 4;
    const int wr = w >> 1, wc = w & 1;
    const int i0 = blockIdx.x * 64, n0 = blockIdx.y * 64;
    f32x4 acc[2][2] = {};
    for (int kc = 0; kc < 256; kc += 32) {
        __syncthreads();
        {
            int r = t >> 2, u = t & 3;
            ushort8 v = *(const ushort8*)(zn + (i0 + r) * 256 + kc + 8 * u);
            *(ushort8*)((char*)&As[r][0] + 16 * u) = v;
        }
        for (int p = 0; p < 8; ++p) {
            int e = t + 256 * p;
            int n = e >> 5, c = e & 31;
            Bs[n][c] = (bf16)(W1[(n0 + n) * 256 + kc + c]);
        }
        __syncthreads();
        bf16x8 af[2], bfr[2];
        for (int mi = 0; mi < 2; ++mi) {
            int m = 32 * wr + 16 * mi + l16;
            af[mi] = frag_from(&As[m][4 * lg], &As[m][4 * lg + 16]);
        }
        for (int ni = 0; ni < 2; ++ni) {
            int n = 32 * wc + 16 * ni + l16;
            bfr[ni] = frag_from(&Bs[n][4 * lg], &Bs[n][4 * lg + 16]);
        }
        for (int mi = 0; mi < 2; ++mi)
            for (int ni = 0; ni < 2; ++ni)
                acc[mi][ni] = MFMA16(af[mi], bfr[ni], acc[mi][ni]);
    }
    for (int ni = 0; ni < 2; ++ni) {
        int n = n0 + 32 * wc + 16 * ni + l16;
        float b_ = b1[n];
        for (int mi = 0; mi < 2; ++mi)
            for (int i = 0; i < 4; ++i) {
                int m = i0 + 32 * wr + 16 * mi + 4 * lg + i;
                float h = acc[mi][ni][i] + b_;
                float g = 0.5f * h * (1.f + erff(h * 0.70710678118f));
                t1[m * 512 + n] = (bf16)g;
            }
    }
}

// ---------------------------------------------------------------------------
// Kernel 5: t = t1 @ W2^T + b2; out[c][i] = x[c][i] + t[i][c] (LDS transpose)
// ---------------------------------------------------------------------------
__global__ __launch_bounds__(256) void k_mlp2(
    const bf16* __restrict__ t1, const float* __restrict__ W2,
    const float* __restrict__ b2, const float* __restrict__ x,
    float* __restrict__ out)
{
    __shared__ bf16 As[64][40];
    __shared__ bf16 Bs[64][40];
    __shared__ float T[64][65];
    const int t = threadIdx.x, lane = t & 63, w = t >> 6;
    const int l16 = lane & 15, lg = lane >> 4;
    const int wr = w >> 1, wc = w & 1;
    const int i0 = blockIdx.x * 64, n0 = blockIdx.y * 64;
    f32x4 acc[2][2] = {};
    for (int kc = 0; kc < 512; kc += 32) {
        __syncthreads();
        {
            int r = t >> 2, u = t & 3;
            ushort8 v = *(const ushort8*)(t1 + (i0 + r) * 512 + kc + 8 * u);
            *(ushort8*)((char*)&As[r][0] + 16 * u) = v;
        }
        for (int p = 0; p < 8; ++p) {
            int e = t + 256 * p;
            int n = e >> 5, c = e & 31;
            Bs[n][c] = (bf16)(W2[(n0 + n) * 512 + kc + c]);
        }
        __syncthreads();
        bf16x8 af[2], bfr[2];
        for (int mi = 0; mi < 2; ++mi) {
            int m = 32 * wr + 16 * mi + l16;
            af[mi] = frag_from(&As[m][4 * lg], &As[m][4 * lg + 16]);
        }
        for (int ni = 0; ni < 2; ++ni) {
            int n = 32 * wc + 16 * ni + l16;
            bfr[ni] = frag_from(&Bs[n][4 * lg], &Bs[n][4 * lg + 16]);
        }
        for (int mi = 0; mi < 2; ++mi)
            for (int ni = 0; ni < 2; ++ni)
                acc[mi][ni] = MFMA16(af[mi], bfr[ni], acc[mi][ni]);
    }
    for (int ni = 0; ni < 2; ++ni) {
        int nn = 32 * wc + 16 * ni + l16;
        float b_ = b2[n0 + nn];
        for (int mi = 0; mi < 2; ++mi)
            for (int i = 0; i < 4; ++i) {
                int mloc = 32 * wr + 16 * mi + 4 * lg + i;
                T[nn][mloc] = acc[mi][ni][i] + b_;
            }
    }
    __syncthreads();
    for (int p = 0; p < 16; ++p) {
        int e = t + 256 * p;              // 0..4095
        int nn = e >> 6, mm = e & 63;
        int c = n0 + nn, m = i0 + mm;
        out[c * 4096 + m] = x[c * 4096 + m] + T[nn][mm];
    }
}

// ---------------------------------------------------------------------------
extern "C" void kernel_launch(void* const* d_in, const int* in_sizes, int n_in,
                              void* d_out, int out_size, void* d_ws, size_t ws_size,
                              hipStream_t stream) {
    (void)in_sizes; (void)n_in; (void)out_size; (void)ws_size;
    const float* x   = (const float*)d_in[0];
    const float* y   = (const float*)d_in[1];
    const float* Wq  = (const float*)d_in[2];
    const float* bq  = (const float*)d_in[3];
    const float* Wk  = (const float*)d_in[4];
    const float* bk  = (const float*)d_in[5];
    const float* Wv  = (const float*)d_in[6];
    const float* bv  = (const float*)d_in[7];
    const float* Wo  = (const float*)d_in[8];
    const float* bo  = (const float*)d_in[9];
    const float* lnw = (const float*)d_in[10];
    const float* lnb = (const float*)d_in[11];
    const float* W1  = (const float*)d_in[12];
    const float* b1  = (const float*)d_in[13];
    const float* W2  = (const float*)d_in[14];
    const float* b2  = (const float*)d_in[15];
    float* out = (float*)d_out;

    char* ws = (char*)d_ws;
    const size_t MB2 = 1u << 21;
    bf16* Qb  = (bf16*)(ws + 0 * MB2);
    bf16* Kb  = (bf16*)(ws + 1 * MB2);
    bf16* Vb  = (bf16*)(ws + 2 * MB2);
    bf16* Vt  = (bf16*)(ws + 3 * MB2);
    bf16* att = (bf16*)(ws + 4 * MB2);
    bf16* zn  = (bf16*)(ws + 5 * MB2);
    bf16* t1  = (bf16*)(ws + 6 * MB2);   // 4 MB

    k_qkv<<<dim3(64, 4, 3), 256, 0, stream>>>(x, y, Wq, bq, Wk, bk, Wv, bv, Qb, Kb, Vb);
    k_transpose<<<dim3(128, 8), 256, 0, stream>>>(Vb, Vt);
    k_flash<<<dim3(128), 256, 0, stream>>>(Qb, Kb, Vt, att);
    k_proj_ln<<<dim3(128), 256, 0, stream>>>(att, Wo, bo, lnw, lnb, zn);
    k_mlp1<<<dim3(64, 8), 256, 0, stream>>>(zn, W1, b1, t1);
    k_mlp2<<<dim3(64, 4), 256, 0, stream>>>(t1, W2, b2, x, out);
}